// Round 1
// baseline (1853.780 us; speedup 1.0000x reference)
//
#include <hip/hip_runtime.h>
#include <math.h>

// ---------------------------------------------------------------------------
// Encoder_352187318911: x[N,512] -> Lin+BN+ELU -> Lin+BN+ELU -> GCN+BN+ReLU
//                       -> GCN+BN -> out[N,32]
// All biases cancel inside training-mode BatchNorm (h - mean(h)) -> skipped.
// ---------------------------------------------------------------------------

__device__ __forceinline__ void atomAddF(float* p, float v) {
  unsafeAtomicAdd(p, v);   // global_atomic_add_f32 (no CAS loop)
}

// ---- degree ---------------------------------------------------------------
__global__ void deg_init_k(float* deg, int N) {
  int i = blockIdx.x * 256 + threadIdx.x;
  if (i < N) deg[i] = 1.0f;           // self-loop
}
__global__ void deg_count_k(const int* __restrict__ dst, float* deg, int E) {
  int e = blockIdx.x * 256 + threadIdx.x;
  if (e < E) atomAddF(&deg[dst[e]], 1.0f);
}
__global__ void dinv_k(const float* __restrict__ deg, float* dinv, int N) {
  int i = blockIdx.x * 256 + threadIdx.x;
  if (i < N) dinv[i] = rsqrtf(deg[i]);  // deg >= 1 always (self-loop)
}

// ---- tiled fp32 GEMM: Y[N,M] = X[N,K] @ W[K,M]; optional self-loop epilogue
// Yself[i][c] = Y[i][c] * dinv[i]^2  (initializes the scatter accumulator)
template<int K, int M>
__global__ __launch_bounds__(256) void gemm_tiled(
    const float* __restrict__ X, const float* __restrict__ W,
    float* __restrict__ Y, float* __restrict__ Yself,
    const float* __restrict__ dinv, int N) {
  constexpr int BM = 64, KT = 16;
  constexpr int MC = M / 16;            // cols per thread
  constexpr int AS = 68;                // padded stride (16B-aligned, <=2-way bank alias)
  __shared__ __align__(16) float As[KT * AS];   // As[k*AS + row] (transposed)
  __shared__ __align__(16) float Bs[KT * M];    // Bs[k*M + col]
  const int tid = threadIdx.x;
  const int tc = tid % 16, tr = tid / 16;
  const int r0 = blockIdx.x * BM;

  float acc[4][MC];
#pragma unroll
  for (int r = 0; r < 4; r++)
#pragma unroll
    for (int c = 0; c < MC; c++) acc[r][c] = 0.f;

  const int arow = tid / 4;             // 0..63
  const int akoff = (tid % 4) * 4;      // 0,4,8,12
  const bool arowok = (r0 + arow) < N;
  const long xbase = (long)(r0 + arow) * K + akoff;
  constexpr int BLD = (KT * M) / 256;   // B elems per thread

  for (int k0 = 0; k0 < K; k0 += KT) {
    float4 av = make_float4(0.f, 0.f, 0.f, 0.f);
    if (arowok) av = *(const float4*)&X[xbase + k0];
    float bv[BLD];
#pragma unroll
    for (int i = 0; i < BLD; i++) bv[i] = W[(long)k0 * M + i * 256 + tid];
    __syncthreads();                    // previous tile fully consumed
    As[(akoff + 0) * AS + arow] = av.x;
    As[(akoff + 1) * AS + arow] = av.y;
    As[(akoff + 2) * AS + arow] = av.z;
    As[(akoff + 3) * AS + arow] = av.w;
#pragma unroll
    for (int i = 0; i < BLD; i++) Bs[i * 256 + tid] = bv[i];
    __syncthreads();
#pragma unroll
    for (int kk = 0; kk < KT; kk++) {
      float4 a = *(const float4*)&As[kk * AS + tr * 4];
      float ar[4] = {a.x, a.y, a.z, a.w};
      float b[MC];
#pragma unroll
      for (int c = 0; c < MC; c++) b[c] = Bs[kk * M + tc * MC + c];
#pragma unroll
      for (int r = 0; r < 4; r++)
#pragma unroll
        for (int c = 0; c < MC; c++) acc[r][c] += ar[r] * b[c];
    }
  }

#pragma unroll
  for (int r = 0; r < 4; r++) {
    int row = r0 + tr * 4 + r;
    if (row < N) {
      float dd = 0.f;
      if (Yself != nullptr) { float di = dinv[row]; dd = di * di; }
#pragma unroll
      for (int c = 0; c < MC; c++) {
        int col = tc * MC + c;
        float v = acc[r][c];
        Y[(long)row * M + col] = v;
        if (Yself != nullptr) Yself[(long)row * M + col] = v * dd;
      }
    }
  }
}

// ---- BN column stats (sum, sumsq) -----------------------------------------
template<int C>
__global__ __launch_bounds__(256) void colstats(const float* __restrict__ H, int N,
                                                float* gsum, float* gsq) {
  constexpr int G = 256 / C;
  const int col = threadIdx.x % C, g = threadIdx.x / C;
  float s = 0.f, q = 0.f;
  for (long r = (long)blockIdx.x * G + g; r < N; r += (long)gridDim.x * G) {
    float v = H[r * C + col];
    s += v; q += v * v;
  }
  __shared__ float ls[256], lq[256];
  ls[threadIdx.x] = s; lq[threadIdx.x] = q;
  __syncthreads();
  if (threadIdx.x < C) {
#pragma unroll
    for (int i = 1; i < G; i++) { s += ls[col + i * C]; q += lq[col + i * C]; }
    atomAddF(&gsum[col], s);
    atomAddF(&gsq[col], q);
  }
}

__global__ void bn_finalize(const float* __restrict__ gsum, const float* __restrict__ gsq,
                            const float* __restrict__ gamma, const float* __restrict__ beta,
                            float* scale, float* shift, int C, float invN, float eps) {
  int c = threadIdx.x;
  if (c >= C) return;
  float mean = gsum[c] * invN;
  float var = fmaxf(gsq[c] * invN - mean * mean, 0.f);
  float sc = gamma[c] * rsqrtf(var + eps);
  scale[c] = sc;
  shift[c] = beta[c] - mean * sc;
}

// ---- BN apply + activation (0=none, 1=relu, 2=elu) ------------------------
template<int C, int ACT>
__global__ __launch_bounds__(256) void bn_apply(const float* __restrict__ X, float* __restrict__ Y,
                                                const float* __restrict__ scale,
                                                const float* __restrict__ shift, long total) {
  long stride = (long)gridDim.x * 256;
  for (long i = (long)blockIdx.x * 256 + threadIdx.x; i < total; i += stride) {
    int c = (int)(i & (C - 1));
    float v = X[i] * scale[c] + shift[c];
    if (ACT == 1) v = fmaxf(v, 0.f);
    if (ACT == 2) v = v > 0.f ? v : (expf(v) - 1.f);
    Y[i] = v;
  }
}

// ---- edge scatter: OUT[d] += HT[s] * dinv[s]*dinv[d] -----------------------
template<int C>
__global__ __launch_bounds__(256) void gcn_scatter(const float* __restrict__ HT,
                                                   const int* __restrict__ src,
                                                   const int* __restrict__ dst,
                                                   const float* __restrict__ dinv,
                                                   float* __restrict__ OUT, int E) {
  constexpr int EPB = 256 / C;
  const int lane = threadIdx.x % C;
  const int eoff = threadIdx.x / C;
  for (long e = (long)blockIdx.x * EPB + eoff; e < E; e += (long)gridDim.x * EPB) {
    int s = src[e], d = dst[e];
    float nrm = dinv[s] * dinv[d];
    float v = HT[(long)s * C + lane] * nrm;
    atomAddF(&OUT[(long)d * C + lane], v);
  }
}

// ---------------------------------------------------------------------------
extern "C" void kernel_launch(void* const* d_in, const int* in_sizes, int n_in,
                              void* d_out, int out_size, void* d_ws, size_t ws_size,
                              hipStream_t stream) {
  const float* x   = (const float*)d_in[0];
  const int* eidx  = (const int*)d_in[1];
  const float* W1  = (const float*)d_in[2];
  const float* g1  = (const float*)d_in[4];
  const float* be1 = (const float*)d_in[5];
  const float* W2  = (const float*)d_in[6];
  const float* g2  = (const float*)d_in[8];
  const float* be2 = (const float*)d_in[9];
  const float* Wg1 = (const float*)d_in[10];
  const float* g3  = (const float*)d_in[12];
  const float* be3 = (const float*)d_in[13];
  const float* Wg2 = (const float*)d_in[14];
  const float* g4  = (const float*)d_in[16];
  const float* be4 = (const float*)d_in[17];
  float* out = (float*)d_out;

  const int N = in_sizes[0] / 512;
  const int E = in_sizes[1] / 2;
  const int* src  = eidx;
  const int* dstp = eidx + E;
  const long Nl = N;

  float* ws   = (float*)d_ws;
  float* h1   = ws;               // N*128
  float* h2   = ws + Nl * 128;    // N*64
  float* deg  = ws + Nl * 192;    // N
  float* dinv = ws + Nl * 193;    // N
  float* S    = ws + Nl * 194;    // 2048 floats of stats
  float* sums = S, *sqs = S + 512, *scale = S + 1024, *shift = S + 1536;
  // phase reuse inside h1's region:
  float* ht   = h1;               // N*64  (gc1 transform)
  float* out1 = h1 + Nl * 64;     // N*64  (gc1 accum, then relu'd input to gc2)
  float* ht2  = h1;               // N*32  (gc2 transform)
  float* out2 = h1 + Nl * 32;     // N*32  (gc2 accum)

  hipMemsetAsync(S, 0, 1024 * sizeof(float), stream);   // zero sums+sqs

  const float invN = 1.0f / (float)N;
  int nbN = (N + 255) / 256;
  int nbE = (E + 255) / 256;
  int gb  = (N + 63) / 64;

  // degree (shared by both GCN layers)
  deg_init_k<<<nbN, 256, 0, stream>>>(deg, N);
  deg_count_k<<<nbE, 256, 0, stream>>>(dstp, deg, E);
  dinv_k<<<nbN, 256, 0, stream>>>(deg, dinv, N);

  // encoder L1: Linear(512,128) -> BN(eps 1e-3) -> ELU
  gemm_tiled<512, 128><<<gb, 256, 0, stream>>>(x, W1, h1, nullptr, nullptr, N);
  colstats<128><<<1024, 256, 0, stream>>>(h1, N, sums + 0, sqs + 0);
  bn_finalize<<<1, 128, 0, stream>>>(sums + 0, sqs + 0, g1, be1, scale + 0, shift + 0, 128, invN, 1e-3f);
  bn_apply<128, 2><<<2048, 256, 0, stream>>>(h1, h1, scale + 0, shift + 0, Nl * 128);

  // encoder L2: Linear(128,64) -> BN(eps 1e-3) -> ELU
  gemm_tiled<128, 64><<<gb, 256, 0, stream>>>(h1, W2, h2, nullptr, nullptr, N);
  colstats<64><<<1024, 256, 0, stream>>>(h2, N, sums + 128, sqs + 128);
  bn_finalize<<<1, 128, 0, stream>>>(sums + 128, sqs + 128, g2, be2, scale + 128, shift + 128, 64, invN, 1e-3f);
  bn_apply<64, 2><<<2048, 256, 0, stream>>>(h2, h2, scale + 128, shift + 128, Nl * 64);

  // gc1: GCNConv(64,64) -> BN(eps 1e-5) -> ReLU
  gemm_tiled<64, 64><<<gb, 256, 0, stream>>>(h2, Wg1, ht, out1, dinv, N);
  gcn_scatter<64><<<8192, 256, 0, stream>>>(ht, src, dstp, dinv, out1, E);
  colstats<64><<<1024, 256, 0, stream>>>(out1, N, sums + 256, sqs + 256);
  bn_finalize<<<1, 128, 0, stream>>>(sums + 256, sqs + 256, g3, be3, scale + 256, shift + 256, 64, invN, 1e-5f);
  bn_apply<64, 1><<<2048, 256, 0, stream>>>(out1, out1, scale + 256, shift + 256, Nl * 64);

  // gc2: GCNConv(64,32) -> BN(eps 1e-5) -> identity
  gemm_tiled<64, 32><<<gb, 256, 0, stream>>>(out1, Wg2, ht2, out2, dinv, N);
  gcn_scatter<32><<<8192, 256, 0, stream>>>(ht2, src, dstp, dinv, out2, E);
  colstats<32><<<1024, 256, 0, stream>>>(out2, N, sums + 384, sqs + 384);
  bn_finalize<<<1, 128, 0, stream>>>(sums + 384, sqs + 384, g4, be4, scale + 384, shift + 384, 32, invN, 1e-5f);
  bn_apply<32, 0><<<2048, 256, 0, stream>>>(out2, out, scale + 384, shift + 384, Nl * 32);
}

// Round 2
// 1309.595 us; speedup vs baseline: 1.4155x; 1.4155x over previous
//
#include <hip/hip_runtime.h>
#include <math.h>

// ---------------------------------------------------------------------------
// Encoder_352187318911: x[N,512] -> Lin+BN+ELU -> Lin+BN+ELU -> GCN+BN+ReLU
//                       -> GCN+BN -> out[N,32]
// Biases cancel inside training-mode BatchNorm -> skipped.
// R2: push-scatter (819 MB atomic writes) -> CSR pull (zero FP atomics),
//     bf16 messages with dinv[s] fused into the transform epilogue.
// ---------------------------------------------------------------------------

typedef unsigned short ushort_t;
typedef unsigned int uint_t;

__device__ __forceinline__ void atomAddF(float* p, float v) {
  unsafeAtomicAdd(p, v);   // global_atomic_add_f32
}
__device__ __forceinline__ ushort_t f2b(float f) {   // fp32 -> bf16 RNE
  uint_t u = __float_as_uint(f);
  return (ushort_t)((u + 0x7FFFu + ((u >> 16) & 1u)) >> 16);
}
__device__ __forceinline__ float b2f(ushort_t b) {
  return __uint_as_float(((uint_t)b) << 16);
}

// ---- degree ---------------------------------------------------------------
__global__ void deg_init_k(float* deg, int N) {
  int i = blockIdx.x * 256 + threadIdx.x;
  if (i < N) deg[i] = 1.0f;           // self-loop
}
__global__ void deg_count_k(const int* __restrict__ dst, float* deg, int E) {
  int e = blockIdx.x * 256 + threadIdx.x;
  if (e < E) atomAddF(&deg[dst[e]], 1.0f);
}
__global__ void dinv_k(const float* __restrict__ deg, float* dinv, int N) {
  int i = blockIdx.x * 256 + threadIdx.x;
  if (i < N) dinv[i] = rsqrtf(deg[i]);  // deg >= 1 (self-loop)
}

// ---- CSR build: exclusive scan of edge counts + bucket fill ---------------
__global__ void scan_blocksum(const float* __restrict__ deg, int* bsum, int N) {
  __shared__ int lds[256];
  int i = blockIdx.x * 256 + threadIdx.x;
  int c = (i < N) ? (int)deg[i] - 1 : 0;    // edge count (deg includes self-loop)
  lds[threadIdx.x] = c; __syncthreads();
  for (int off = 128; off > 0; off >>= 1) {
    if (threadIdx.x < off) lds[threadIdx.x] += lds[threadIdx.x + off];
    __syncthreads();
  }
  if (threadIdx.x == 0) bsum[blockIdx.x] = lds[0];
}
__global__ void scan_partials(const int* __restrict__ bsum, int* boff, int NB) {
  __shared__ int lds[1024];
  int t = threadIdx.x;
  int v = (t < NB) ? bsum[t] : 0;
  lds[t] = v; __syncthreads();
  for (int off = 1; off < 1024; off <<= 1) {
    int add = (t >= off) ? lds[t - off] : 0;
    __syncthreads();
    lds[t] += add;
    __syncthreads();
  }
  if (t < NB) boff[t] = lds[t] - v;   // exclusive
}
__global__ void scan_final(const float* __restrict__ deg, const int* __restrict__ boff,
                           int* rowptr, int* cursor, int N) {
  __shared__ int lds[256];
  int t = threadIdx.x;
  int i = blockIdx.x * 256 + t;
  int c = (i < N) ? (int)deg[i] - 1 : 0;
  lds[t] = c; __syncthreads();
  for (int off = 1; off < 256; off <<= 1) {
    int add = (t >= off) ? lds[t - off] : 0;
    __syncthreads();
    lds[t] += add;
    __syncthreads();
  }
  if (i < N) {
    int ex = boff[blockIdx.x] + lds[t] - c;   // exclusive offset
    rowptr[i] = ex;
    cursor[i] = ex;
    if (i == N - 1) rowptr[N] = ex + c;
  }
}
__global__ void csr_fill(const int* __restrict__ src, const int* __restrict__ dst,
                         int* cursor, int* csr, int E) {
  int e = blockIdx.x * 256 + threadIdx.x;
  if (e < E) {
    int d = dst[e];
    int pos = atomicAdd(&cursor[d], 1);
    csr[pos] = src[e];
  }
}

// ---- tiled fp32 GEMM: Y[N,M] = X[N,K] @ W[K,M]
// EPI=0: Yf = result (fp32).  EPI=1: Yb = bf16( result * dinv[row] ).
template<int K, int M, int EPI>
__global__ __launch_bounds__(256) void gemm_tiled(
    const float* __restrict__ X, const float* __restrict__ W,
    float* __restrict__ Yf, ushort_t* __restrict__ Yb,
    const float* __restrict__ dinv, int N) {
  constexpr int BM = 64, KT = 16;
  constexpr int MC = M / 16;
  constexpr int AS = 68;
  __shared__ __align__(16) float As[KT * AS];
  __shared__ __align__(16) float Bs[KT * M];
  const int tid = threadIdx.x;
  const int tc = tid % 16, tr = tid / 16;
  const int r0 = blockIdx.x * BM;

  float acc[4][MC];
#pragma unroll
  for (int r = 0; r < 4; r++)
#pragma unroll
    for (int c = 0; c < MC; c++) acc[r][c] = 0.f;

  const int arow = tid / 4;
  const int akoff = (tid % 4) * 4;
  const bool arowok = (r0 + arow) < N;
  const long xbase = (long)(r0 + arow) * K + akoff;
  constexpr int BLD = (KT * M) / 256;

  for (int k0 = 0; k0 < K; k0 += KT) {
    float4 av = make_float4(0.f, 0.f, 0.f, 0.f);
    if (arowok) av = *(const float4*)&X[xbase + k0];
    float bv[BLD];
#pragma unroll
    for (int i = 0; i < BLD; i++) bv[i] = W[(long)k0 * M + i * 256 + tid];
    __syncthreads();
    As[(akoff + 0) * AS + arow] = av.x;
    As[(akoff + 1) * AS + arow] = av.y;
    As[(akoff + 2) * AS + arow] = av.z;
    As[(akoff + 3) * AS + arow] = av.w;
#pragma unroll
    for (int i = 0; i < BLD; i++) Bs[i * 256 + tid] = bv[i];
    __syncthreads();
#pragma unroll
    for (int kk = 0; kk < KT; kk++) {
      float4 a = *(const float4*)&As[kk * AS + tr * 4];
      float ar[4] = {a.x, a.y, a.z, a.w};
      float b[MC];
#pragma unroll
      for (int c = 0; c < MC; c++) b[c] = Bs[kk * M + tc * MC + c];
#pragma unroll
      for (int r = 0; r < 4; r++)
#pragma unroll
        for (int c = 0; c < MC; c++) acc[r][c] += ar[r] * b[c];
    }
  }

#pragma unroll
  for (int r = 0; r < 4; r++) {
    int row = r0 + tr * 4 + r;
    if (row < N) {
      float dsc = (EPI == 1) ? dinv[row] : 1.f;
#pragma unroll
      for (int c = 0; c < MC; c++) {
        int col = tc * MC + c;
        float v = acc[r][c];
        if (EPI == 0) Yf[(long)row * M + col] = v;
        else          Yb[(long)row * M + col] = f2b(v * dsc);
      }
    }
  }
}

// ---- pull aggregation: out[d][c] = dinv[d] * (htn[d][c] + sum_s htn[s][c])
template<int C>
__global__ __launch_bounds__(256) void gcn_pull(const ushort_t* __restrict__ htn,
                                                const int* __restrict__ rowptr,
                                                const int* __restrict__ csr,
                                                const float* __restrict__ dinv,
                                                float* __restrict__ OUT, int N) {
  constexpr int NPB = 256 / C;
  const int node = blockIdx.x * NPB + threadIdx.x / C;
  const int c = threadIdx.x % C;
  if (node >= N) return;
  const int st = rowptr[node], en = rowptr[node + 1];
  float acc = b2f(htn[(long)node * C + c]);   // self-loop term
  int j = st;
  for (; j + 4 <= en; j += 4) {
    int s0 = csr[j], s1 = csr[j + 1], s2 = csr[j + 2], s3 = csr[j + 3];
    float v0 = b2f(htn[(long)s0 * C + c]);
    float v1 = b2f(htn[(long)s1 * C + c]);
    float v2 = b2f(htn[(long)s2 * C + c]);
    float v3 = b2f(htn[(long)s3 * C + c]);
    acc += v0 + v1 + v2 + v3;
  }
  for (; j < en; j++) acc += b2f(htn[(long)csr[j] * C + c]);
  OUT[(long)node * C + c] = acc * dinv[node];
}

// ---- BN column stats ------------------------------------------------------
template<int C>
__global__ __launch_bounds__(256) void colstats(const float* __restrict__ H, int N,
                                                float* gsum, float* gsq) {
  constexpr int G = 256 / C;
  const int col = threadIdx.x % C, g = threadIdx.x / C;
  float s = 0.f, q = 0.f;
  for (long r = (long)blockIdx.x * G + g; r < N; r += (long)gridDim.x * G) {
    float v = H[r * C + col];
    s += v; q += v * v;
  }
  __shared__ float ls[256], lq[256];
  ls[threadIdx.x] = s; lq[threadIdx.x] = q;
  __syncthreads();
  if (threadIdx.x < C) {
#pragma unroll
    for (int i = 1; i < G; i++) { s += ls[col + i * C]; q += lq[col + i * C]; }
    atomAddF(&gsum[col], s);
    atomAddF(&gsq[col], q);
  }
}

__global__ void bn_finalize(const float* __restrict__ gsum, const float* __restrict__ gsq,
                            const float* __restrict__ gamma, const float* __restrict__ beta,
                            float* scale, float* shift, int C, float invN, float eps) {
  int c = threadIdx.x;
  if (c >= C) return;
  float mean = gsum[c] * invN;
  float var = fmaxf(gsq[c] * invN - mean * mean, 0.f);
  float sc = gamma[c] * rsqrtf(var + eps);
  scale[c] = sc;
  shift[c] = beta[c] - mean * sc;
}

// ---- BN apply + activation (0=none, 1=relu, 2=elu) ------------------------
template<int C, int ACT>
__global__ __launch_bounds__(256) void bn_apply(const float* __restrict__ X, float* __restrict__ Y,
                                                const float* __restrict__ scale,
                                                const float* __restrict__ shift, long total) {
  long stride = (long)gridDim.x * 256;
  for (long i = (long)blockIdx.x * 256 + threadIdx.x; i < total; i += stride) {
    int c = (int)(i & (C - 1));
    float v = X[i] * scale[c] + shift[c];
    if (ACT == 1) v = fmaxf(v, 0.f);
    if (ACT == 2) v = v > 0.f ? v : (expf(v) - 1.f);
    Y[i] = v;
  }
}

// ---------------------------------------------------------------------------
extern "C" void kernel_launch(void* const* d_in, const int* in_sizes, int n_in,
                              void* d_out, int out_size, void* d_ws, size_t ws_size,
                              hipStream_t stream) {
  const float* x   = (const float*)d_in[0];
  const int* eidx  = (const int*)d_in[1];
  const float* W1  = (const float*)d_in[2];
  const float* g1  = (const float*)d_in[4];
  const float* be1 = (const float*)d_in[5];
  const float* W2  = (const float*)d_in[6];
  const float* g2  = (const float*)d_in[8];
  const float* be2 = (const float*)d_in[9];
  const float* Wg1 = (const float*)d_in[10];
  const float* g3  = (const float*)d_in[12];
  const float* be3 = (const float*)d_in[13];
  const float* Wg2 = (const float*)d_in[14];
  const float* g4  = (const float*)d_in[16];
  const float* be4 = (const float*)d_in[17];
  float* out = (float*)d_out;

  const int N = in_sizes[0] / 512;
  const int E = in_sizes[1] / 2;
  const int* src  = eidx;
  const int* dstp = eidx + E;
  const long Nl = N;

  float* ws = (float*)d_ws;
  float* h1 = ws;                        // N*128 f32 (later: out1 + htn)
  float* h2 = ws + Nl * 128;             // N*64 f32  (later: htn2 + out2)
  int* csr    = (int*)(ws + Nl * 192);   // E
  int* rowptr = csr + E;                 // N+1
  int* cursor = rowptr + N + 1;          // N
  float* deg  = (float*)(cursor + N);    // N
  float* dinv = deg + N;                 // N
  float* S    = dinv + N;                // 2048 stats
  float* sums = S, *sqs = S + 512, *scale = S + 1024, *shift = S + 1536;

  // gc1 temporaries live in h1's region (free after layer-2 GEMM consumes h1)
  float* out1    = h1;                          // N*64 f32
  ushort_t* htn  = (ushort_t*)(h1 + Nl * 64);   // N*64 bf16
  // gc2 temporaries live in h2's region (free after gc1 transform consumes h2)
  ushort_t* htn2 = (ushort_t*)h2;               // N*32 bf16
  float* out2    = h2 + Nl * 32;                // N*32 f32

  hipMemsetAsync(S, 0, 1024 * sizeof(float), stream);

  const float invN = 1.0f / (float)N;
  const int nbN = (N + 255) / 256;
  const int nbE = (E + 255) / 256;
  const int gb  = (N + 63) / 64;

  // degree + dinv (shared by both GCN layers)
  deg_init_k<<<nbN, 256, 0, stream>>>(deg, N);
  deg_count_k<<<nbE, 256, 0, stream>>>(dstp, deg, E);
  dinv_k<<<nbN, 256, 0, stream>>>(deg, dinv, N);

  // CSR by destination
  scan_blocksum<<<nbN, 256, 0, stream>>>(deg, cursor /*tmp bsum*/, N);
  scan_partials<<<1, 1024, 0, stream>>>(cursor, rowptr /*tmp boff*/, nbN);
  // copy boff out of rowptr's way: scan_final reads boff, writes rowptr+cursor.
  // Use the tail of S (stats area is 2048 floats; boff needs nbN<=1024 ints) —
  // instead just use a dedicated kernel ordering: read boff from rowptr BEFORE
  // overwriting. scan_final reads boff[blockIdx.x] once at start; but rowptr[i]
  // writes could race with other blocks' boff reads. Avoid by using csr[] head
  // as the boff buffer (csr not yet filled).
  // (Re-run partials into csr head to keep it simple and race-free.)
  scan_partials<<<1, 1024, 0, stream>>>(cursor, csr /*boff*/, nbN);
  scan_final<<<nbN, 256, 0, stream>>>(deg, csr /*boff*/, rowptr, cursor, N);
  csr_fill<<<nbE, 256, 0, stream>>>(src, dstp, cursor, csr, E);

  // encoder L1: Linear(512,128) -> BN(1e-3) -> ELU
  gemm_tiled<512, 128, 0><<<gb, 256, 0, stream>>>(x, W1, h1, nullptr, nullptr, N);
  colstats<128><<<1024, 256, 0, stream>>>(h1, N, sums + 0, sqs + 0);
  bn_finalize<<<1, 128, 0, stream>>>(sums + 0, sqs + 0, g1, be1, scale + 0, shift + 0, 128, invN, 1e-3f);
  bn_apply<128, 2><<<2048, 256, 0, stream>>>(h1, h1, scale + 0, shift + 0, Nl * 128);

  // encoder L2: Linear(128,64) -> BN(1e-3) -> ELU
  gemm_tiled<128, 64, 0><<<gb, 256, 0, stream>>>(h1, W2, h2, nullptr, nullptr, N);
  colstats<64><<<1024, 256, 0, stream>>>(h2, N, sums + 128, sqs + 128);
  bn_finalize<<<1, 128, 0, stream>>>(sums + 128, sqs + 128, g2, be2, scale + 128, shift + 128, 64, invN, 1e-3f);
  bn_apply<64, 2><<<2048, 256, 0, stream>>>(h2, h2, scale + 128, shift + 128, Nl * 64);

  // gc1: GCNConv(64,64) -> BN(1e-5) -> ReLU
  gemm_tiled<64, 64, 1><<<gb, 256, 0, stream>>>(h2, Wg1, nullptr, htn, dinv, N);
  gcn_pull<64><<<(N + 3) / 4, 256, 0, stream>>>(htn, rowptr, csr, dinv, out1, N);
  colstats<64><<<1024, 256, 0, stream>>>(out1, N, sums + 256, sqs + 256);
  bn_finalize<<<1, 128, 0, stream>>>(sums + 256, sqs + 256, g3, be3, scale + 256, shift + 256, 64, invN, 1e-5f);
  bn_apply<64, 1><<<2048, 256, 0, stream>>>(out1, out1, scale + 256, shift + 256, Nl * 64);

  // gc2: GCNConv(64,32) -> BN(1e-5)
  gemm_tiled<64, 32, 1><<<gb, 256, 0, stream>>>(out1, Wg2, nullptr, htn2, dinv, N);
  gcn_pull<32><<<(N + 7) / 8, 256, 0, stream>>>(htn2, rowptr, csr, dinv, out2, N);
  colstats<32><<<1024, 256, 0, stream>>>(out2, N, sums + 384, sqs + 384);
  bn_finalize<<<1, 128, 0, stream>>>(sums + 384, sqs + 384, g4, be4, scale + 384, shift + 384, 32, invN, 1e-5f);
  bn_apply<32, 0><<<2048, 256, 0, stream>>>(out2, out, scale + 384, shift + 384, Nl * 32);
}

// Round 3
// 1106.054 us; speedup vs baseline: 1.6760x; 1.1840x over previous
//
#include <hip/hip_runtime.h>
#include <math.h>

// ---------------------------------------------------------------------------
// Encoder_352187318911: x[N,512] -> Lin+BN+ELU -> Lin+BN+ELU -> GCN+BN+ReLU
//                       -> GCN+BN -> out[N,32]
// Biases cancel inside training-mode BatchNorm -> skipped.
// R3: two-level counting-sort CSR build (dense writes, LDS cursors) replaces
//     csr_fill (194 MB of partial-line scattered writes). BN+act for layers
//     1-3 fused into the next GEMM's A-tile load.
// ---------------------------------------------------------------------------

typedef unsigned short ushort_t;
typedef unsigned int uint_t;

constexpr int NPB = 192;    // nodes per coarse bucket (phase-2 csr region ~25KB)
constexpr int NBMAX = 576;  // LDS arrays sized for ceil(100k/192)=521 buckets

__device__ __forceinline__ void atomAddF(float* p, float v) {
  unsafeAtomicAdd(p, v);   // global_atomic_add_f32
}
__device__ __forceinline__ ushort_t f2b(float f) {   // fp32 -> bf16 RNE
  uint_t u = __float_as_uint(f);
  return (ushort_t)((u + 0x7FFFu + ((u >> 16) & 1u)) >> 16);
}
__device__ __forceinline__ float b2f(ushort_t b) {
  return __uint_as_float(((uint_t)b) << 16);
}

// ---- degree ---------------------------------------------------------------
__global__ void deg_init_k(float* deg, int N) {
  int i = blockIdx.x * 256 + threadIdx.x;
  if (i < N) deg[i] = 1.0f;           // self-loop
}
__global__ void deg_count_k(const int* __restrict__ dst, float* deg, int E) {
  int e = blockIdx.x * 256 + threadIdx.x;
  if (e < E) atomAddF(&deg[dst[e]], 1.0f);
}
__global__ void dinv_k(const float* __restrict__ deg, float* dinv, int N) {
  int i = blockIdx.x * 256 + threadIdx.x;
  if (i < N) dinv[i] = rsqrtf(deg[i]);  // deg >= 1 (self-loop)
}

// ---- rowptr: exclusive scan of per-node edge counts -----------------------
__global__ void scan_blocksum(const float* __restrict__ deg, int* bsum, int N) {
  __shared__ int lds[256];
  int i = blockIdx.x * 256 + threadIdx.x;
  int c = (i < N) ? (int)deg[i] - 1 : 0;
  lds[threadIdx.x] = c; __syncthreads();
  for (int off = 128; off > 0; off >>= 1) {
    if (threadIdx.x < off) lds[threadIdx.x] += lds[threadIdx.x + off];
    __syncthreads();
  }
  if (threadIdx.x == 0) bsum[blockIdx.x] = lds[0];
}
__global__ void scan_partials(const int* __restrict__ bsum, int* boff, int NB) {
  __shared__ int lds[1024];
  int t = threadIdx.x;
  int v = (t < NB) ? bsum[t] : 0;
  lds[t] = v; __syncthreads();
  for (int off = 1; off < 1024; off <<= 1) {
    int add = (t >= off) ? lds[t - off] : 0;
    __syncthreads();
    lds[t] += add;
    __syncthreads();
  }
  if (t < NB) boff[t] = lds[t] - v;   // exclusive
}
__global__ void scan_final(const float* __restrict__ deg, const int* __restrict__ boff,
                           int* rowptr, int N) {
  __shared__ int lds[256];
  int t = threadIdx.x;
  int i = blockIdx.x * 256 + t;
  int c = (i < N) ? (int)deg[i] - 1 : 0;
  lds[t] = c; __syncthreads();
  for (int off = 1; off < 256; off <<= 1) {
    int add = (t >= off) ? lds[t - off] : 0;
    __syncthreads();
    lds[t] += add;
    __syncthreads();
  }
  if (i < N) {
    int ex = boff[blockIdx.x] + lds[t] - c;
    rowptr[i] = ex;
    if (i == N - 1) rowptr[N] = ex + c;
  }
}

// ---- CSR build, phase 0: per-bucket global cursors ------------------------
__global__ void init_gcur(const int* __restrict__ rowptr, int* gcur, int NB) {
  int b = blockIdx.x * 256 + threadIdx.x;
  if (b < NB) gcur[b] = rowptr[b * NPB];
}

// ---- CSR build, phase 1: chunk -> coarse buckets (dense pair writes) ------
__global__ __launch_bounds__(256) void csr_bucket(const int* __restrict__ src,
                                                  const int* __restrict__ dst,
                                                  int* __restrict__ gcur,
                                                  int2* __restrict__ pair,
                                                  int E, int NB, int chunk) {
  __shared__ int hist[NBMAX], base[NBMAX], cnt[NBMAX];
  const int t = threadIdx.x;
  const int c0 = blockIdx.x * chunk;
  const int c1 = min(c0 + chunk, E);
  for (int b = t; b < NB; b += 256) hist[b] = 0;
  __syncthreads();
  for (int e = c0 + t; e < c1; e += 256) atomicAdd(&hist[dst[e] / NPB], 1);
  __syncthreads();
  for (int b = t; b < NB; b += 256) {
    int h = hist[b];
    base[b] = h ? atomicAdd(&gcur[b], h) : 0;
    cnt[b] = 0;
  }
  __syncthreads();
  for (int e = c0 + t; e < c1; e += 256) {
    int d = dst[e];
    int b = d / NPB;
    int off = atomicAdd(&cnt[b], 1);
    pair[base[b] + off] = make_int2(src[e], d);
  }
}

// ---- CSR build, phase 2: per-bucket exact placement (LDS cursors) ---------
__global__ __launch_bounds__(256) void csr_scatter(const int2* __restrict__ pair,
                                                   const int* __restrict__ rowptr,
                                                   int* __restrict__ csr, int N) {
  __shared__ int lcur[NPB];
  const int n0 = blockIdx.x * NPB;
  const int n1 = min(n0 + NPB, N);
  const int t = threadIdx.x;
  for (int i = t; i < n1 - n0; i += 256) lcur[i] = rowptr[n0 + i];
  __syncthreads();
  const int s0 = rowptr[n0], s1 = rowptr[n1];
  for (int i = s0 + t; i < s1; i += 256) {
    int2 p = pair[i];
    int pos = atomicAdd(&lcur[p.y - n0], 1);
    csr[pos] = p.x;
  }
}

// ---- tiled fp32 GEMM: Y[N,M] = act(bn(X))[N,K] @ W[K,M]
// AIN: 0 = raw A, 1 = BN+ELU on A-load, 2 = BN+ReLU on A-load
// EPI: 0 = Yf fp32, 1 = Yb bf16( result * dinv[row] )
template<int K, int M, int EPI, int AIN>
__global__ __launch_bounds__(256) void gemm_tiled(
    const float* __restrict__ X, const float* __restrict__ W,
    float* __restrict__ Yf, ushort_t* __restrict__ Yb,
    const float* __restrict__ dinv,
    const float* __restrict__ ascale, const float* __restrict__ ashift, int N) {
  constexpr int BM = 64, KT = 16;
  constexpr int MC = M / 16;
  constexpr int AS = 68;
  __shared__ __align__(16) float As[KT * AS];
  __shared__ __align__(16) float Bs[KT * M];
  const int tid = threadIdx.x;
  const int tc = tid % 16, tr = tid / 16;
  const int r0 = blockIdx.x * BM;

  float acc[4][MC];
#pragma unroll
  for (int r = 0; r < 4; r++)
#pragma unroll
    for (int c = 0; c < MC; c++) acc[r][c] = 0.f;

  const int arow = tid / 4;
  const int akoff = (tid % 4) * 4;
  const bool arowok = (r0 + arow) < N;
  const long xbase = (long)(r0 + arow) * K + akoff;
  constexpr int BLD = (KT * M) / 256;

  for (int k0 = 0; k0 < K; k0 += KT) {
    float4 av = make_float4(0.f, 0.f, 0.f, 0.f);
    if (arowok) {
      av = *(const float4*)&X[xbase + k0];
      if (AIN != 0) {
        float4 sc = *(const float4*)&ascale[k0 + akoff];
        float4 sh = *(const float4*)&ashift[k0 + akoff];
        av.x = av.x * sc.x + sh.x;
        av.y = av.y * sc.y + sh.y;
        av.z = av.z * sc.z + sh.z;
        av.w = av.w * sc.w + sh.w;
        if (AIN == 1) {        // ELU
          av.x = av.x > 0.f ? av.x : (expf(av.x) - 1.f);
          av.y = av.y > 0.f ? av.y : (expf(av.y) - 1.f);
          av.z = av.z > 0.f ? av.z : (expf(av.z) - 1.f);
          av.w = av.w > 0.f ? av.w : (expf(av.w) - 1.f);
        } else {               // ReLU
          av.x = fmaxf(av.x, 0.f); av.y = fmaxf(av.y, 0.f);
          av.z = fmaxf(av.z, 0.f); av.w = fmaxf(av.w, 0.f);
        }
      }
    }
    float bv[BLD];
#pragma unroll
    for (int i = 0; i < BLD; i++) bv[i] = W[(long)k0 * M + i * 256 + tid];
    __syncthreads();
    As[(akoff + 0) * AS + arow] = av.x;
    As[(akoff + 1) * AS + arow] = av.y;
    As[(akoff + 2) * AS + arow] = av.z;
    As[(akoff + 3) * AS + arow] = av.w;
#pragma unroll
    for (int i = 0; i < BLD; i++) Bs[i * 256 + tid] = bv[i];
    __syncthreads();
#pragma unroll
    for (int kk = 0; kk < KT; kk++) {
      float4 a = *(const float4*)&As[kk * AS + tr * 4];
      float ar[4] = {a.x, a.y, a.z, a.w};
      float b[MC];
#pragma unroll
      for (int c = 0; c < MC; c++) b[c] = Bs[kk * M + tc * MC + c];
#pragma unroll
      for (int r = 0; r < 4; r++)
#pragma unroll
        for (int c = 0; c < MC; c++) acc[r][c] += ar[r] * b[c];
    }
  }

#pragma unroll
  for (int r = 0; r < 4; r++) {
    int row = r0 + tr * 4 + r;
    if (row < N) {
      float dsc = (EPI == 1) ? dinv[row] : 1.f;
#pragma unroll
      for (int c = 0; c < MC; c++) {
        int col = tc * MC + c;
        float v = acc[r][c];
        if (EPI == 0) Yf[(long)row * M + col] = v;
        else          Yb[(long)row * M + col] = f2b(v * dsc);
      }
    }
  }
}

// ---- pull aggregation: out[d][c] = dinv[d] * (htn[d][c] + sum_s htn[s][c])
template<int C>
__global__ __launch_bounds__(256) void gcn_pull(const ushort_t* __restrict__ htn,
                                                const int* __restrict__ rowptr,
                                                const int* __restrict__ csr,
                                                const float* __restrict__ dinv,
                                                float* __restrict__ OUT, int N) {
  constexpr int NPBk = 256 / C;
  const int node = blockIdx.x * NPBk + threadIdx.x / C;
  const int c = threadIdx.x % C;
  if (node >= N) return;
  const int st = rowptr[node], en = rowptr[node + 1];
  float acc = b2f(htn[(long)node * C + c]);   // self-loop term
  int j = st;
  for (; j + 4 <= en; j += 4) {
    int s0 = csr[j], s1 = csr[j + 1], s2 = csr[j + 2], s3 = csr[j + 3];
    float v0 = b2f(htn[(long)s0 * C + c]);
    float v1 = b2f(htn[(long)s1 * C + c]);
    float v2 = b2f(htn[(long)s2 * C + c]);
    float v3 = b2f(htn[(long)s3 * C + c]);
    acc += v0 + v1 + v2 + v3;
  }
  for (; j < en; j++) acc += b2f(htn[(long)csr[j] * C + c]);
  OUT[(long)node * C + c] = acc * dinv[node];
}

// ---- BN column stats ------------------------------------------------------
template<int C>
__global__ __launch_bounds__(256) void colstats(const float* __restrict__ H, int N,
                                                float* gsum, float* gsq) {
  constexpr int G = 256 / C;
  const int col = threadIdx.x % C, g = threadIdx.x / C;
  float s = 0.f, q = 0.f;
  for (long r = (long)blockIdx.x * G + g; r < N; r += (long)gridDim.x * G) {
    float v = H[r * C + col];
    s += v; q += v * v;
  }
  __shared__ float ls[256], lq[256];
  ls[threadIdx.x] = s; lq[threadIdx.x] = q;
  __syncthreads();
  if (threadIdx.x < C) {
#pragma unroll
    for (int i = 1; i < G; i++) { s += ls[col + i * C]; q += lq[col + i * C]; }
    atomAddF(&gsum[col], s);
    atomAddF(&gsq[col], q);
  }
}

__global__ void bn_finalize(const float* __restrict__ gsum, const float* __restrict__ gsq,
                            const float* __restrict__ gamma, const float* __restrict__ beta,
                            float* scale, float* shift, int C, float invN, float eps) {
  int c = threadIdx.x;
  if (c >= C) return;
  float mean = gsum[c] * invN;
  float var = fmaxf(gsq[c] * invN - mean * mean, 0.f);
  float sc = gamma[c] * rsqrtf(var + eps);
  scale[c] = sc;
  shift[c] = beta[c] - mean * sc;
}

// ---- BN apply (final layer only) ------------------------------------------
template<int C, int ACT>
__global__ __launch_bounds__(256) void bn_apply(const float* __restrict__ X, float* __restrict__ Y,
                                                const float* __restrict__ scale,
                                                const float* __restrict__ shift, long total) {
  long stride = (long)gridDim.x * 256;
  for (long i = (long)blockIdx.x * 256 + threadIdx.x; i < total; i += stride) {
    int c = (int)(i & (C - 1));
    float v = X[i] * scale[c] + shift[c];
    if (ACT == 1) v = fmaxf(v, 0.f);
    if (ACT == 2) v = v > 0.f ? v : (expf(v) - 1.f);
    Y[i] = v;
  }
}

// ---------------------------------------------------------------------------
extern "C" void kernel_launch(void* const* d_in, const int* in_sizes, int n_in,
                              void* d_out, int out_size, void* d_ws, size_t ws_size,
                              hipStream_t stream) {
  const float* x   = (const float*)d_in[0];
  const int* eidx  = (const int*)d_in[1];
  const float* W1  = (const float*)d_in[2];
  const float* g1  = (const float*)d_in[4];
  const float* be1 = (const float*)d_in[5];
  const float* W2  = (const float*)d_in[6];
  const float* g2  = (const float*)d_in[8];
  const float* be2 = (const float*)d_in[9];
  const float* Wg1 = (const float*)d_in[10];
  const float* g3  = (const float*)d_in[12];
  const float* be3 = (const float*)d_in[13];
  const float* Wg2 = (const float*)d_in[14];
  const float* g4  = (const float*)d_in[16];
  const float* be4 = (const float*)d_in[17];
  float* out = (float*)d_out;

  const int N = in_sizes[0] / 512;
  const int E = in_sizes[1] / 2;
  const int* src  = eidx;
  const int* dstp = eidx + E;
  const long Nl = N;
  const int NB = (N + NPB - 1) / NPB;     // coarse buckets

  float* ws = (float*)d_ws;
  float* h1 = ws;                        // N*128 f32 (pre-GEMM1: pair buffer)
  float* h2 = ws + Nl * 128;             // N*64 f32
  int* csr    = (int*)(ws + Nl * 192);   // E
  int* rowptr = csr + E;                 // N+1
  int* gcur   = rowptr + N + 1;          // NB (+pad to 640)
  float* deg  = (float*)(gcur + 640);    // N
  float* dinv = deg + N;                 // N
  float* S    = dinv + N;                // 2048 stats
  float* sums = S, *sqs = S + 512, *scale = S + 1024, *shift = S + 1536;

  int2* pair = (int2*)h1;                // E pairs (25.6MB <= h1's 51.2MB)

  float* out1    = h1;                          // N*64 f32
  ushort_t* htn  = (ushort_t*)(h1 + Nl * 64);   // N*64 bf16
  ushort_t* htn2 = (ushort_t*)h2;               // N*32 bf16
  float* out2    = h2 + Nl * 32;                // N*32 f32

  hipMemsetAsync(S, 0, 1024 * sizeof(float), stream);

  const float invN = 1.0f / (float)N;
  const int nbN = (N + 255) / 256;
  const int nbE = (E + 255) / 256;
  const int gb  = (N + 63) / 64;
  const int chunk = (E + 255) / 256;

  // degree + dinv (shared by both GCN layers)
  deg_init_k<<<nbN, 256, 0, stream>>>(deg, N);
  deg_count_k<<<nbE, 256, 0, stream>>>(dstp, deg, E);
  dinv_k<<<nbN, 256, 0, stream>>>(deg, dinv, N);

  // rowptr (exclusive scan); bsum lives in gcur, boff in csr head (both dead after)
  scan_blocksum<<<nbN, 256, 0, stream>>>(deg, gcur, N);
  scan_partials<<<1, 1024, 0, stream>>>(gcur, csr, nbN);
  scan_final<<<nbN, 256, 0, stream>>>(deg, csr, rowptr, N);

  // CSR build: bucket pass (dense pair writes) + per-bucket exact placement
  init_gcur<<<(NB + 255) / 256, 256, 0, stream>>>(rowptr, gcur, NB);
  csr_bucket<<<256, 256, 0, stream>>>(src, dstp, gcur, pair, E, NB, chunk);
  csr_scatter<<<NB, 256, 0, stream>>>(pair, rowptr, csr, N);

  // encoder L1: Linear(512,128); BN stats only (apply fused into next GEMM)
  gemm_tiled<512, 128, 0, 0><<<gb, 256, 0, stream>>>(x, W1, h1, nullptr, nullptr, nullptr, nullptr, N);
  colstats<128><<<1024, 256, 0, stream>>>(h1, N, sums + 0, sqs + 0);
  bn_finalize<<<1, 128, 0, stream>>>(sums + 0, sqs + 0, g1, be1, scale + 0, shift + 0, 128, invN, 1e-3f);

  // encoder L2: A = ELU(BN(h1)) fused; BN stats only
  gemm_tiled<128, 64, 0, 1><<<gb, 256, 0, stream>>>(h1, W2, h2, nullptr, nullptr, scale + 0, shift + 0, N);
  colstats<64><<<1024, 256, 0, stream>>>(h2, N, sums + 128, sqs + 128);
  bn_finalize<<<1, 128, 0, stream>>>(sums + 128, sqs + 128, g2, be2, scale + 128, shift + 128, 64, invN, 1e-3f);

  // gc1 transform: A = ELU(BN(h2)) fused; epilogue htn = bf16(h@Wg1 * dinv)
  gemm_tiled<64, 64, 1, 1><<<gb, 256, 0, stream>>>(h2, Wg1, nullptr, htn, dinv, scale + 128, shift + 128, N);
  gcn_pull<64><<<(N + 3) / 4, 256, 0, stream>>>(htn, rowptr, csr, dinv, out1, N);
  colstats<64><<<1024, 256, 0, stream>>>(out1, N, sums + 256, sqs + 256);
  bn_finalize<<<1, 128, 0, stream>>>(sums + 256, sqs + 256, g3, be3, scale + 256, shift + 256, 64, invN, 1e-5f);

  // gc2 transform: A = ReLU(BN(out1)) fused; epilogue htn2 = bf16(h@Wg2 * dinv)
  gemm_tiled<64, 32, 1, 2><<<gb, 256, 0, stream>>>(out1, Wg2, nullptr, htn2, dinv, scale + 256, shift + 256, N);
  gcn_pull<32><<<(N + 7) / 8, 256, 0, stream>>>(htn2, rowptr, csr, dinv, out2, N);
  colstats<32><<<1024, 256, 0, stream>>>(out2, N, sums + 384, sqs + 384);
  bn_finalize<<<1, 128, 0, stream>>>(sums + 384, sqs + 384, g4, be4, scale + 384, shift + 384, 32, invN, 1e-5f);
  bn_apply<32, 0><<<2048, 256, 0, stream>>>(out2, out, scale + 384, shift + 384, Nl * 32);
}

// Round 4
// 1017.487 us; speedup vs baseline: 1.8219x; 1.0870x over previous
//
#include <hip/hip_runtime.h>
#include <math.h>

// ---------------------------------------------------------------------------
// Encoder_352187318911: x[N,512] -> Lin+BN+ELU -> Lin+BN+ELU -> GCN+BN+ReLU
//                       -> GCN+BN -> out[N,32]
// Biases cancel inside training-mode BatchNorm -> skipped.
// R4: GEMM1 (100k x 512 x 128) moved to bf16 MFMA (16x16x32), A converted
//     on-the-fly during LDS staging, W1 pre-transposed to bf16 once.
// ---------------------------------------------------------------------------

typedef unsigned short ushort_t;
typedef unsigned int uint_t;
typedef float f32x4 __attribute__((ext_vector_type(4)));
typedef short bf16x8 __attribute__((ext_vector_type(8)));

constexpr int NPB = 192;    // nodes per coarse bucket (CSR build)
constexpr int NBMAX = 576;

__device__ __forceinline__ void atomAddF(float* p, float v) {
  unsafeAtomicAdd(p, v);
}
__device__ __forceinline__ ushort_t f2b(float f) {   // fp32 -> bf16 RNE
  uint_t u = __float_as_uint(f);
  return (ushort_t)((u + 0x7FFFu + ((u >> 16) & 1u)) >> 16);
}
__device__ __forceinline__ float b2f(ushort_t b) {
  return __uint_as_float(((uint_t)b) << 16);
}

// ---- degree ---------------------------------------------------------------
__global__ void deg_init_k(float* deg, int N) {
  int i = blockIdx.x * 256 + threadIdx.x;
  if (i < N) deg[i] = 1.0f;
}
__global__ void deg_count_k(const int* __restrict__ dst, float* deg, int E) {
  int e = blockIdx.x * 256 + threadIdx.x;
  if (e < E) atomAddF(&deg[dst[e]], 1.0f);
}
__global__ void dinv_k(const float* __restrict__ deg, float* dinv, int N) {
  int i = blockIdx.x * 256 + threadIdx.x;
  if (i < N) dinv[i] = rsqrtf(deg[i]);
}

// ---- rowptr scan ----------------------------------------------------------
__global__ void scan_blocksum(const float* __restrict__ deg, int* bsum, int N) {
  __shared__ int lds[256];
  int i = blockIdx.x * 256 + threadIdx.x;
  int c = (i < N) ? (int)deg[i] - 1 : 0;
  lds[threadIdx.x] = c; __syncthreads();
  for (int off = 128; off > 0; off >>= 1) {
    if (threadIdx.x < off) lds[threadIdx.x] += lds[threadIdx.x + off];
    __syncthreads();
  }
  if (threadIdx.x == 0) bsum[blockIdx.x] = lds[0];
}
__global__ void scan_partials(const int* __restrict__ bsum, int* boff, int NB) {
  __shared__ int lds[1024];
  int t = threadIdx.x;
  int v = (t < NB) ? bsum[t] : 0;
  lds[t] = v; __syncthreads();
  for (int off = 1; off < 1024; off <<= 1) {
    int add = (t >= off) ? lds[t - off] : 0;
    __syncthreads();
    lds[t] += add;
    __syncthreads();
  }
  if (t < NB) boff[t] = lds[t] - v;
}
__global__ void scan_final(const float* __restrict__ deg, const int* __restrict__ boff,
                           int* rowptr, int N) {
  __shared__ int lds[256];
  int t = threadIdx.x;
  int i = blockIdx.x * 256 + t;
  int c = (i < N) ? (int)deg[i] - 1 : 0;
  lds[t] = c; __syncthreads();
  for (int off = 1; off < 256; off <<= 1) {
    int add = (t >= off) ? lds[t - off] : 0;
    __syncthreads();
    lds[t] += add;
    __syncthreads();
  }
  if (i < N) {
    int ex = boff[blockIdx.x] + lds[t] - c;
    rowptr[i] = ex;
    if (i == N - 1) rowptr[N] = ex + c;
  }
}

// ---- CSR build ------------------------------------------------------------
__global__ void init_gcur(const int* __restrict__ rowptr, int* gcur, int NB) {
  int b = blockIdx.x * 256 + threadIdx.x;
  if (b < NB) gcur[b] = rowptr[b * NPB];
}
__global__ __launch_bounds__(256) void csr_bucket(const int* __restrict__ src,
                                                  const int* __restrict__ dst,
                                                  int* __restrict__ gcur,
                                                  int2* __restrict__ pair,
                                                  int E, int NB, int chunk) {
  __shared__ int hist[NBMAX], base[NBMAX], cnt[NBMAX];
  const int t = threadIdx.x;
  const int c0 = blockIdx.x * chunk;
  const int c1 = min(c0 + chunk, E);
  for (int b = t; b < NB; b += 256) hist[b] = 0;
  __syncthreads();
  for (int e = c0 + t; e < c1; e += 256) atomicAdd(&hist[dst[e] / NPB], 1);
  __syncthreads();
  for (int b = t; b < NB; b += 256) {
    int h = hist[b];
    base[b] = h ? atomicAdd(&gcur[b], h) : 0;
    cnt[b] = 0;
  }
  __syncthreads();
  for (int e = c0 + t; e < c1; e += 256) {
    int d = dst[e];
    int b = d / NPB;
    int off = atomicAdd(&cnt[b], 1);
    pair[base[b] + off] = make_int2(src[e], d);
  }
}
__global__ __launch_bounds__(256) void csr_scatter(const int2* __restrict__ pair,
                                                   const int* __restrict__ rowptr,
                                                   int* __restrict__ csr, int N) {
  __shared__ int lcur[NPB];
  const int n0 = blockIdx.x * NPB;
  const int n1 = min(n0 + NPB, N);
  const int t = threadIdx.x;
  for (int i = t; i < n1 - n0; i += 256) lcur[i] = rowptr[n0 + i];
  __syncthreads();
  const int s0 = rowptr[n0], s1 = rowptr[n1];
  for (int i = s0 + t; i < s1; i += 256) {
    int2 p = pair[i];
    int pos = atomicAdd(&lcur[p.y - n0], 1);
    csr[pos] = p.x;
  }
}

// ---- W1 prep: fp32 [512][128] -> bf16 transposed [128][512] ---------------
__global__ void w1_prep(const float* __restrict__ W1, ushort_t* __restrict__ Wt) {
  int idx = blockIdx.x * 256 + threadIdx.x;   // 65536 total
  int k = idx >> 7, m = idx & 127;
  Wt[m * 512 + k] = f2b(W1[idx]);
}

// ---- MFMA GEMM1: Y[N,128] = X[N,512] @ W1[512,128], bf16 inputs/fp32 acc --
// Wt is W1 transposed [128][512] bf16. 128x128 tile, BK=64, 4 waves.
__global__ __launch_bounds__(256) void mfma_gemm1(
    const float* __restrict__ X, const ushort_t* __restrict__ Wt,
    float* __restrict__ Y, int N) {
  constexpr int SA = 72;                     // LDS row stride (bf16): 144B = 9*16B
  __shared__ ushort_t As[128 * SA];          // A-tile [128 rows][64 k] bf16
  __shared__ ushort_t Bs[128 * SA];          // B-tile [128 n][64 k] bf16
  const int t = threadIdx.x;
  const int w = t >> 6, lane = t & 63;
  const int ln = lane & 15, quad = lane >> 4;
  const int r0 = blockIdx.x * 128;

  f32x4 acc[2][8];
#pragma unroll
  for (int mt = 0; mt < 2; mt++)
#pragma unroll
    for (int nt = 0; nt < 8; nt++) acc[mt][nt] = (f32x4)(0.f);

  for (int k0 = 0; k0 < 512; k0 += 64) {
    // load A: 128x64 fp32, 8 float4/thread, fully coalesced
    float4 av[8];
#pragma unroll
    for (int j = 0; j < 8; j++) {
      int idx = j * 256 + t;                 // 0..2047 float4 slots
      int row = idx >> 4, col = (idx & 15) << 2;
      av[j] = (r0 + row < N) ? *(const float4*)&X[(long)(r0 + row) * 512 + k0 + col]
                             : make_float4(0.f, 0.f, 0.f, 0.f);
    }
    // load B: 128x64 bf16, 4 x 16B/thread
    int4 bv[4];
#pragma unroll
    for (int j = 0; j < 4; j++) {
      int chunk = j * 256 + t;               // 0..1023 16B chunks
      int row = chunk >> 3, c16 = chunk & 7;
      bv[j] = *(const int4*)&Wt[row * 512 + k0 + c16 * 8];
    }
    __syncthreads();                         // previous tile consumed
#pragma unroll
    for (int j = 0; j < 8; j++) {
      int idx = j * 256 + t;
      int row = idx >> 4, col = (idx & 15) << 2;
      ushort_t p[4] = {f2b(av[j].x), f2b(av[j].y), f2b(av[j].z), f2b(av[j].w)};
      *(uint2*)&As[row * SA + col] = *(uint2*)p;   // 8B write
    }
#pragma unroll
    for (int j = 0; j < 4; j++) {
      int chunk = j * 256 + t;
      int row = chunk >> 3, c16 = chunk & 7;
      *(int4*)&Bs[row * SA + c16 * 8] = bv[j];     // 16B write
    }
    __syncthreads();
#pragma unroll
    for (int kk = 0; kk < 64; kk += 32) {
      bf16x8 af[2];
#pragma unroll
      for (int mt = 0; mt < 2; mt++)
        af[mt] = *(const bf16x8*)&As[(w * 32 + mt * 16 + ln) * SA + kk + quad * 8];
#pragma unroll
      for (int nt = 0; nt < 8; nt++) {
        bf16x8 bf = *(const bf16x8*)&Bs[(nt * 16 + ln) * SA + kk + quad * 8];
#pragma unroll
        for (int mt = 0; mt < 2; mt++)
          acc[mt][nt] = __builtin_amdgcn_mfma_f32_16x16x32_bf16(af[mt], bf, acc[mt][nt], 0, 0, 0);
      }
    }
  }

  // epilogue: D[row=(quad*4+r)][col=ln] per tile
#pragma unroll
  for (int mt = 0; mt < 2; mt++) {
#pragma unroll
    for (int r = 0; r < 4; r++) {
      int row = r0 + w * 32 + mt * 16 + quad * 4 + r;
      if (row < N) {
#pragma unroll
        for (int nt = 0; nt < 8; nt++)
          Y[(long)row * 128 + nt * 16 + ln] = acc[mt][nt][r];
      }
    }
  }
}

// ---- tiled fp32 GEMM (layers 2-4): Y[N,M] = act(bn(X))[N,K] @ W[K,M]
// AIN: 0 = raw A, 1 = BN+ELU on A-load, 2 = BN+ReLU on A-load
// EPI: 0 = Yf fp32, 1 = Yb bf16( result * dinv[row] )
template<int K, int M, int EPI, int AIN>
__global__ __launch_bounds__(256) void gemm_tiled(
    const float* __restrict__ X, const float* __restrict__ W,
    float* __restrict__ Yf, ushort_t* __restrict__ Yb,
    const float* __restrict__ dinv,
    const float* __restrict__ ascale, const float* __restrict__ ashift, int N) {
  constexpr int BM = 64, KT = 16;
  constexpr int MC = M / 16;
  constexpr int AS = 68;
  __shared__ __align__(16) float As[KT * AS];
  __shared__ __align__(16) float Bs[KT * M];
  const int tid = threadIdx.x;
  const int tc = tid % 16, tr = tid / 16;
  const int r0 = blockIdx.x * BM;

  float acc[4][MC];
#pragma unroll
  for (int r = 0; r < 4; r++)
#pragma unroll
    for (int c = 0; c < MC; c++) acc[r][c] = 0.f;

  const int arow = tid / 4;
  const int akoff = (tid % 4) * 4;
  const bool arowok = (r0 + arow) < N;
  const long xbase = (long)(r0 + arow) * K + akoff;
  constexpr int BLD = (KT * M) / 256;

  for (int k0 = 0; k0 < K; k0 += KT) {
    float4 av = make_float4(0.f, 0.f, 0.f, 0.f);
    if (arowok) {
      av = *(const float4*)&X[xbase + k0];
      if (AIN != 0) {
        float4 sc = *(const float4*)&ascale[k0 + akoff];
        float4 sh = *(const float4*)&ashift[k0 + akoff];
        av.x = av.x * sc.x + sh.x;
        av.y = av.y * sc.y + sh.y;
        av.z = av.z * sc.z + sh.z;
        av.w = av.w * sc.w + sh.w;
        if (AIN == 1) {
          av.x = av.x > 0.f ? av.x : (expf(av.x) - 1.f);
          av.y = av.y > 0.f ? av.y : (expf(av.y) - 1.f);
          av.z = av.z > 0.f ? av.z : (expf(av.z) - 1.f);
          av.w = av.w > 0.f ? av.w : (expf(av.w) - 1.f);
        } else {
          av.x = fmaxf(av.x, 0.f); av.y = fmaxf(av.y, 0.f);
          av.z = fmaxf(av.z, 0.f); av.w = fmaxf(av.w, 0.f);
        }
      }
    }
    float bv[BLD];
#pragma unroll
    for (int i = 0; i < BLD; i++) bv[i] = W[(long)k0 * M + i * 256 + tid];
    __syncthreads();
    As[(akoff + 0) * AS + arow] = av.x;
    As[(akoff + 1) * AS + arow] = av.y;
    As[(akoff + 2) * AS + arow] = av.z;
    As[(akoff + 3) * AS + arow] = av.w;
#pragma unroll
    for (int i = 0; i < BLD; i++) Bs[i * 256 + tid] = bv[i];
    __syncthreads();
#pragma unroll
    for (int kk = 0; kk < KT; kk++) {
      float4 a = *(const float4*)&As[kk * AS + tr * 4];
      float ar[4] = {a.x, a.y, a.z, a.w};
      float b[MC];
#pragma unroll
      for (int c = 0; c < MC; c++) b[c] = Bs[kk * M + tc * MC + c];
#pragma unroll
      for (int r = 0; r < 4; r++)
#pragma unroll
        for (int c = 0; c < MC; c++) acc[r][c] += ar[r] * b[c];
    }
  }

#pragma unroll
  for (int r = 0; r < 4; r++) {
    int row = r0 + tr * 4 + r;
    if (row < N) {
      float dsc = (EPI == 1) ? dinv[row] : 1.f;
#pragma unroll
      for (int c = 0; c < MC; c++) {
        int col = tc * MC + c;
        float v = acc[r][c];
        if (EPI == 0) Yf[(long)row * M + col] = v;
        else          Yb[(long)row * M + col] = f2b(v * dsc);
      }
    }
  }
}

// ---- pull aggregation -----------------------------------------------------
template<int C>
__global__ __launch_bounds__(256) void gcn_pull(const ushort_t* __restrict__ htn,
                                                const int* __restrict__ rowptr,
                                                const int* __restrict__ csr,
                                                const float* __restrict__ dinv,
                                                float* __restrict__ OUT, int N) {
  constexpr int NPBk = 256 / C;
  const int node = blockIdx.x * NPBk + threadIdx.x / C;
  const int c = threadIdx.x % C;
  if (node >= N) return;
  const int st = rowptr[node], en = rowptr[node + 1];
  float acc = b2f(htn[(long)node * C + c]);
  int j = st;
  for (; j + 4 <= en; j += 4) {
    int s0 = csr[j], s1 = csr[j + 1], s2 = csr[j + 2], s3 = csr[j + 3];
    float v0 = b2f(htn[(long)s0 * C + c]);
    float v1 = b2f(htn[(long)s1 * C + c]);
    float v2 = b2f(htn[(long)s2 * C + c]);
    float v3 = b2f(htn[(long)s3 * C + c]);
    acc += v0 + v1 + v2 + v3;
  }
  for (; j < en; j++) acc += b2f(htn[(long)csr[j] * C + c]);
  OUT[(long)node * C + c] = acc * dinv[node];
}

// ---- BN column stats ------------------------------------------------------
template<int C>
__global__ __launch_bounds__(256) void colstats(const float* __restrict__ H, int N,
                                                float* gsum, float* gsq) {
  constexpr int G = 256 / C;
  const int col = threadIdx.x % C, g = threadIdx.x / C;
  float s = 0.f, q = 0.f;
  for (long r = (long)blockIdx.x * G + g; r < N; r += (long)gridDim.x * G) {
    float v = H[r * C + col];
    s += v; q += v * v;
  }
  __shared__ float ls[256], lq[256];
  ls[threadIdx.x] = s; lq[threadIdx.x] = q;
  __syncthreads();
  if (threadIdx.x < C) {
#pragma unroll
    for (int i = 1; i < G; i++) { s += ls[col + i * C]; q += lq[col + i * C]; }
    atomAddF(&gsum[col], s);
    atomAddF(&gsq[col], q);
  }
}

__global__ void bn_finalize(const float* __restrict__ gsum, const float* __restrict__ gsq,
                            const float* __restrict__ gamma, const float* __restrict__ beta,
                            float* scale, float* shift, int C, float invN, float eps) {
  int c = threadIdx.x;
  if (c >= C) return;
  float mean = gsum[c] * invN;
  float var = fmaxf(gsq[c] * invN - mean * mean, 0.f);
  float sc = gamma[c] * rsqrtf(var + eps);
  scale[c] = sc;
  shift[c] = beta[c] - mean * sc;
}

// ---- BN apply (final layer only) ------------------------------------------
template<int C, int ACT>
__global__ __launch_bounds__(256) void bn_apply(const float* __restrict__ X, float* __restrict__ Y,
                                                const float* __restrict__ scale,
                                                const float* __restrict__ shift, long total) {
  long stride = (long)gridDim.x * 256;
  for (long i = (long)blockIdx.x * 256 + threadIdx.x; i < total; i += stride) {
    int c = (int)(i & (C - 1));
    float v = X[i] * scale[c] + shift[c];
    if (ACT == 1) v = fmaxf(v, 0.f);
    if (ACT == 2) v = v > 0.f ? v : (expf(v) - 1.f);
    Y[i] = v;
  }
}

// ---------------------------------------------------------------------------
extern "C" void kernel_launch(void* const* d_in, const int* in_sizes, int n_in,
                              void* d_out, int out_size, void* d_ws, size_t ws_size,
                              hipStream_t stream) {
  const float* x   = (const float*)d_in[0];
  const int* eidx  = (const int*)d_in[1];
  const float* W1  = (const float*)d_in[2];
  const float* g1  = (const float*)d_in[4];
  const float* be1 = (const float*)d_in[5];
  const float* W2  = (const float*)d_in[6];
  const float* g2  = (const float*)d_in[8];
  const float* be2 = (const float*)d_in[9];
  const float* Wg1 = (const float*)d_in[10];
  const float* g3  = (const float*)d_in[12];
  const float* be3 = (const float*)d_in[13];
  const float* Wg2 = (const float*)d_in[14];
  const float* g4  = (const float*)d_in[16];
  const float* be4 = (const float*)d_in[17];
  float* out = (float*)d_out;

  const int N = in_sizes[0] / 512;
  const int E = in_sizes[1] / 2;
  const int* src  = eidx;
  const int* dstp = eidx + E;
  const long Nl = N;
  const int NB = (N + NPB - 1) / NPB;

  float* ws = (float*)d_ws;
  float* h1 = ws;                        // N*128 f32 (pre-GEMM1: pair buffer)
  float* h2 = ws + Nl * 128;             // N*64 f32
  int* csr    = (int*)(ws + Nl * 192);   // E
  int* rowptr = csr + E;                 // N+1
  int* gcur   = rowptr + N + 1;          // NB (pad 640)
  float* deg  = (float*)(gcur + 640);    // N
  float* dinv = deg + N;                 // N
  float* S    = dinv + N;                // 2048 stats
  float* sums = S, *sqs = S + 512, *scale = S + 1024, *shift = S + 1536;
  ushort_t* Wt = (ushort_t*)(S + 2048);  // 128*512 bf16 (128 KB)

  int2* pair = (int2*)h1;                // E pairs (25.6MB)

  float* out1    = h1;                          // N*64 f32
  ushort_t* htn  = (ushort_t*)(h1 + Nl * 64);   // N*64 bf16
  ushort_t* htn2 = (ushort_t*)h2;               // N*32 bf16
  float* out2    = h2 + Nl * 32;                // N*32 f32

  hipMemsetAsync(S, 0, 1024 * sizeof(float), stream);

  const float invN = 1.0f / (float)N;
  const int nbN = (N + 255) / 256;
  const int nbE = (E + 255) / 256;
  const int gb  = (N + 63) / 64;
  const int chunk = (E + 255) / 256;

  // W1 -> bf16 transposed (independent of everything else)
  w1_prep<<<256, 256, 0, stream>>>(W1, Wt);

  // degree + dinv
  deg_init_k<<<nbN, 256, 0, stream>>>(deg, N);
  deg_count_k<<<nbE, 256, 0, stream>>>(dstp, deg, E);
  dinv_k<<<nbN, 256, 0, stream>>>(deg, dinv, N);

  // rowptr scan (bsum in gcur, boff in csr head; both dead after)
  scan_blocksum<<<nbN, 256, 0, stream>>>(deg, gcur, N);
  scan_partials<<<1, 1024, 0, stream>>>(gcur, csr, nbN);
  scan_final<<<nbN, 256, 0, stream>>>(deg, csr, rowptr, N);

  // CSR build
  init_gcur<<<(NB + 255) / 256, 256, 0, stream>>>(rowptr, gcur, NB);
  csr_bucket<<<256, 256, 0, stream>>>(src, dstp, gcur, pair, E, NB, chunk);
  csr_scatter<<<NB, 256, 0, stream>>>(pair, rowptr, csr, N);

  // encoder L1: Linear(512,128) via bf16 MFMA; BN stats only
  mfma_gemm1<<<(N + 127) / 128, 256, 0, stream>>>(x, Wt, h1, N);
  colstats<128><<<1024, 256, 0, stream>>>(h1, N, sums + 0, sqs + 0);
  bn_finalize<<<1, 128, 0, stream>>>(sums + 0, sqs + 0, g1, be1, scale + 0, shift + 0, 128, invN, 1e-3f);

  // encoder L2: A = ELU(BN(h1)) fused
  gemm_tiled<128, 64, 0, 1><<<gb, 256, 0, stream>>>(h1, W2, h2, nullptr, nullptr, scale + 0, shift + 0, N);
  colstats<64><<<1024, 256, 0, stream>>>(h2, N, sums + 128, sqs + 128);
  bn_finalize<<<1, 128, 0, stream>>>(sums + 128, sqs + 128, g2, be2, scale + 128, shift + 128, 64, invN, 1e-3f);

  // gc1: A = ELU(BN(h2)) fused; epilogue htn = bf16(h@Wg1 * dinv)
  gemm_tiled<64, 64, 1, 1><<<gb, 256, 0, stream>>>(h2, Wg1, nullptr, htn, dinv, scale + 128, shift + 128, N);
  gcn_pull<64><<<(N + 3) / 4, 256, 0, stream>>>(htn, rowptr, csr, dinv, out1, N);
  colstats<64><<<1024, 256, 0, stream>>>(out1, N, sums + 256, sqs + 256);
  bn_finalize<<<1, 128, 0, stream>>>(sums + 256, sqs + 256, g3, be3, scale + 256, shift + 256, 64, invN, 1e-5f);

  // gc2: A = ReLU(BN(out1)) fused; epilogue htn2 = bf16(h@Wg2 * dinv)
  gemm_tiled<64, 32, 1, 2><<<gb, 256, 0, stream>>>(out1, Wg2, nullptr, htn2, dinv, scale + 256, shift + 256, N);
  gcn_pull<32><<<(N + 7) / 8, 256, 0, stream>>>(htn2, rowptr, csr, dinv, out2, N);
  colstats<32><<<1024, 256, 0, stream>>>(out2, N, sums + 384, sqs + 384);
  bn_finalize<<<1, 128, 0, stream>>>(sums + 384, sqs + 384, g4, be4, scale + 384, shift + 384, 32, invN, 1e-5f);
  bn_apply<32, 0><<<2048, 256, 0, stream>>>(out2, out, scale + 384, shift + 384, Nl * 32);
}

// Round 5
// 884.897 us; speedup vs baseline: 2.0949x; 1.1498x over previous
//
#include <hip/hip_runtime.h>
#include <math.h>

// ---------------------------------------------------------------------------
// Encoder_352187318911: x[N,512] -> Lin+BN+ELU -> Lin+BN+ELU -> GCN+BN+ReLU
//                       -> GCN+BN -> out[N,32]
// Biases cancel inside training-mode BatchNorm -> skipped.
// R5: all E-scale global atomics removed. Degree/rowptr/CSR now built via
//     coarse buckets: LDS histograms + per-bucket LDS cursors. (R4 lesson:
//     each device-scope atomic writes ~32B through to HBM -> 100 MB storm.)
// ---------------------------------------------------------------------------

typedef unsigned short ushort_t;
typedef unsigned int uint_t;
typedef float f32x4 __attribute__((ext_vector_type(4)));
typedef short bf16x8 __attribute__((ext_vector_type(8)));

constexpr int NPB = 192;    // nodes per coarse bucket
constexpr int NBMAX = 576;  // LDS hist capacity >= ceil(100k/192)=521

__device__ __forceinline__ void atomAddF(float* p, float v) {
  unsafeAtomicAdd(p, v);
}
__device__ __forceinline__ ushort_t f2b(float f) {   // fp32 -> bf16 RNE
  uint_t u = __float_as_uint(f);
  return (ushort_t)((u + 0x7FFFu + ((u >> 16) & 1u)) >> 16);
}
__device__ __forceinline__ float b2f(ushort_t b) {
  return __uint_as_float(((uint_t)b) << 16);
}

// ---- CSR build, phase 0: per-WG-chunk LDS histogram -> global bucket counts
__global__ __launch_bounds__(256) void bucket_count(const int* __restrict__ dst,
                                                    int* __restrict__ bcnt,
                                                    int E, int NB, int chunk) {
  __shared__ int hist[NBMAX];
  const int t = threadIdx.x;
  const int c0 = blockIdx.x * chunk;
  const int c1 = min(c0 + chunk, E);
  for (int b = t; b < NB; b += 256) hist[b] = 0;
  __syncthreads();
  for (int e = c0 + t; e < c1; e += 256) atomicAdd(&hist[dst[e] / NPB], 1);
  __syncthreads();
  for (int b = t; b < NB; b += 256)
    if (hist[b]) atomicAdd(&bcnt[b], hist[b]);
}

// ---- phase 1: scan bucket counts -> bucket bases + cursors ----------------
__global__ void bucket_scan(const int* __restrict__ bcnt, int* __restrict__ bbase,
                            int* __restrict__ gcur, int NB, int E) {
  __shared__ int lds[1024];
  int t = threadIdx.x;
  int v = (t < NB) ? bcnt[t] : 0;
  lds[t] = v; __syncthreads();
  for (int off = 1; off < 1024; off <<= 1) {
    int add = (t >= off) ? lds[t - off] : 0;
    __syncthreads();
    lds[t] += add;
    __syncthreads();
  }
  if (t < NB) {
    int ex = lds[t] - v;
    bbase[t] = ex;
    gcur[t] = ex;
  }
  if (t == 0) bbase[NB] = E;
}

// ---- phase 2: chunk -> coarse buckets (dense pair writes) -----------------
__global__ __launch_bounds__(256) void csr_bucket(const int* __restrict__ src,
                                                  const int* __restrict__ dst,
                                                  int* __restrict__ gcur,
                                                  int2* __restrict__ pair,
                                                  int E, int NB, int chunk) {
  __shared__ int hist[NBMAX], base[NBMAX], cnt[NBMAX];
  const int t = threadIdx.x;
  const int c0 = blockIdx.x * chunk;
  const int c1 = min(c0 + chunk, E);
  for (int b = t; b < NB; b += 256) hist[b] = 0;
  __syncthreads();
  for (int e = c0 + t; e < c1; e += 256) atomicAdd(&hist[dst[e] / NPB], 1);
  __syncthreads();
  for (int b = t; b < NB; b += 256) {
    int h = hist[b];
    base[b] = h ? atomicAdd(&gcur[b], h) : 0;
    cnt[b] = 0;
  }
  __syncthreads();
  for (int e = c0 + t; e < c1; e += 256) {
    int d = dst[e];
    int b = d / NPB;
    int off = atomicAdd(&cnt[b], 1);
    pair[base[b] + off] = make_int2(src[e], d);
  }
}

// ---- phase 3: per-bucket deg+dinv+rowptr+scatter, all cursors in LDS ------
__global__ __launch_bounds__(256) void bucket_node(const int2* __restrict__ pair,
                                                   const int* __restrict__ bbase,
                                                   int* __restrict__ rowptr,
                                                   int* __restrict__ csr,
                                                   float* __restrict__ dinv, int N) {
  __shared__ int cnt[NPB];
  __shared__ int sb[256];
  const int b = blockIdx.x;
  const int t = threadIdx.x;
  const int n0 = b * NPB;
  const int n1 = min(n0 + NPB, N);
  const int s0 = bbase[b], s1 = bbase[b + 1];
  if (t < NPB) cnt[t] = 0;
  __syncthreads();
  for (int i = s0 + t; i < s1; i += 256) atomicAdd(&cnt[pair[i].y - n0], 1);
  __syncthreads();
  int v = (t < NPB) ? cnt[t] : 0;
  sb[t] = v; __syncthreads();
  for (int off = 1; off < 256; off <<= 1) {
    int add = (t >= off) ? sb[t - off] : 0;
    __syncthreads();
    sb[t] += add;
    __syncthreads();
  }
  int excl = sb[t] - v;
  if (t < n1 - n0) {
    rowptr[n0 + t] = s0 + excl;
    dinv[n0 + t] = rsqrtf((float)(v + 1));   // +1 self-loop
  }
  if (b == gridDim.x - 1 && t == 0) rowptr[N] = s1;
  __syncthreads();
  if (t < NPB) cnt[t] = s0 + excl;           // reuse as cursor
  __syncthreads();
  for (int i = s0 + t; i < s1; i += 256) {
    int2 p = pair[i];
    int pos = atomicAdd(&cnt[p.y - n0], 1);
    csr[pos] = p.x;
  }
}

// ---- W1 prep: fp32 [512][128] -> bf16 transposed [128][512] ---------------
__global__ void w1_prep(const float* __restrict__ W1, ushort_t* __restrict__ Wt) {
  int idx = blockIdx.x * 256 + threadIdx.x;   // 65536 total
  int k = idx >> 7, m = idx & 127;
  Wt[m * 512 + k] = f2b(W1[idx]);
}

// ---- MFMA GEMM1: Y[N,128] = X[N,512] @ W1[512,128] ------------------------
__global__ __launch_bounds__(256) void mfma_gemm1(
    const float* __restrict__ X, const ushort_t* __restrict__ Wt,
    float* __restrict__ Y, int N) {
  constexpr int SA = 72;                     // bf16 row stride: 144B = 9*16B
  __shared__ ushort_t As[128 * SA];
  __shared__ ushort_t Bs[128 * SA];
  const int t = threadIdx.x;
  const int w = t >> 6, lane = t & 63;
  const int ln = lane & 15, quad = lane >> 4;
  const int r0 = blockIdx.x * 128;

  f32x4 acc[2][8];
#pragma unroll
  for (int mt = 0; mt < 2; mt++)
#pragma unroll
    for (int nt = 0; nt < 8; nt++) acc[mt][nt] = (f32x4)(0.f);

  for (int k0 = 0; k0 < 512; k0 += 64) {
    float4 av[8];
#pragma unroll
    for (int j = 0; j < 8; j++) {
      int idx = j * 256 + t;
      int row = idx >> 4, col = (idx & 15) << 2;
      av[j] = (r0 + row < N) ? *(const float4*)&X[(long)(r0 + row) * 512 + k0 + col]
                             : make_float4(0.f, 0.f, 0.f, 0.f);
    }
    int4 bv[4];
#pragma unroll
    for (int j = 0; j < 4; j++) {
      int chunk = j * 256 + t;
      int row = chunk >> 3, c16 = chunk & 7;
      bv[j] = *(const int4*)&Wt[row * 512 + k0 + c16 * 8];
    }
    __syncthreads();
#pragma unroll
    for (int j = 0; j < 8; j++) {
      int idx = j * 256 + t;
      int row = idx >> 4, col = (idx & 15) << 2;
      ushort_t p[4] = {f2b(av[j].x), f2b(av[j].y), f2b(av[j].z), f2b(av[j].w)};
      *(uint2*)&As[row * SA + col] = *(uint2*)p;
    }
#pragma unroll
    for (int j = 0; j < 4; j++) {
      int chunk = j * 256 + t;
      int row = chunk >> 3, c16 = chunk & 7;
      *(int4*)&Bs[row * SA + c16 * 8] = bv[j];
    }
    __syncthreads();
#pragma unroll
    for (int kk = 0; kk < 64; kk += 32) {
      bf16x8 af[2];
#pragma unroll
      for (int mt = 0; mt < 2; mt++)
        af[mt] = *(const bf16x8*)&As[(w * 32 + mt * 16 + ln) * SA + kk + quad * 8];
#pragma unroll
      for (int nt = 0; nt < 8; nt++) {
        bf16x8 bf = *(const bf16x8*)&Bs[(nt * 16 + ln) * SA + kk + quad * 8];
#pragma unroll
        for (int mt = 0; mt < 2; mt++)
          acc[mt][nt] = __builtin_amdgcn_mfma_f32_16x16x32_bf16(af[mt], bf, acc[mt][nt], 0, 0, 0);
      }
    }
  }

#pragma unroll
  for (int mt = 0; mt < 2; mt++) {
#pragma unroll
    for (int r = 0; r < 4; r++) {
      int row = r0 + w * 32 + mt * 16 + quad * 4 + r;
      if (row < N) {
#pragma unroll
        for (int nt = 0; nt < 8; nt++)
          Y[(long)row * 128 + nt * 16 + ln] = acc[mt][nt][r];
      }
    }
  }
}

// ---- tiled fp32 GEMM (layers 2-4) -----------------------------------------
// AIN: 0 = raw A, 1 = BN+ELU on A-load, 2 = BN+ReLU on A-load
// EPI: 0 = Yf fp32, 1 = Yb bf16( result * dinv[row] )
template<int K, int M, int EPI, int AIN>
__global__ __launch_bounds__(256) void gemm_tiled(
    const float* __restrict__ X, const float* __restrict__ W,
    float* __restrict__ Yf, ushort_t* __restrict__ Yb,
    const float* __restrict__ dinv,
    const float* __restrict__ ascale, const float* __restrict__ ashift, int N) {
  constexpr int BM = 64, KT = 16;
  constexpr int MC = M / 16;
  constexpr int AS = 68;
  __shared__ __align__(16) float As[KT * AS];
  __shared__ __align__(16) float Bs[KT * M];
  const int tid = threadIdx.x;
  const int tc = tid % 16, tr = tid / 16;
  const int r0 = blockIdx.x * BM;

  float acc[4][MC];
#pragma unroll
  for (int r = 0; r < 4; r++)
#pragma unroll
    for (int c = 0; c < MC; c++) acc[r][c] = 0.f;

  const int arow = tid / 4;
  const int akoff = (tid % 4) * 4;
  const bool arowok = (r0 + arow) < N;
  const long xbase = (long)(r0 + arow) * K + akoff;
  constexpr int BLD = (KT * M) / 256;

  for (int k0 = 0; k0 < K; k0 += KT) {
    float4 av = make_float4(0.f, 0.f, 0.f, 0.f);
    if (arowok) {
      av = *(const float4*)&X[xbase + k0];
      if (AIN != 0) {
        float4 sc = *(const float4*)&ascale[k0 + akoff];
        float4 sh = *(const float4*)&ashift[k0 + akoff];
        av.x = av.x * sc.x + sh.x;
        av.y = av.y * sc.y + sh.y;
        av.z = av.z * sc.z + sh.z;
        av.w = av.w * sc.w + sh.w;
        if (AIN == 1) {
          av.x = av.x > 0.f ? av.x : (expf(av.x) - 1.f);
          av.y = av.y > 0.f ? av.y : (expf(av.y) - 1.f);
          av.z = av.z > 0.f ? av.z : (expf(av.z) - 1.f);
          av.w = av.w > 0.f ? av.w : (expf(av.w) - 1.f);
        } else {
          av.x = fmaxf(av.x, 0.f); av.y = fmaxf(av.y, 0.f);
          av.z = fmaxf(av.z, 0.f); av.w = fmaxf(av.w, 0.f);
        }
      }
    }
    float bv[BLD];
#pragma unroll
    for (int i = 0; i < BLD; i++) bv[i] = W[(long)k0 * M + i * 256 + tid];
    __syncthreads();
    As[(akoff + 0) * AS + arow] = av.x;
    As[(akoff + 1) * AS + arow] = av.y;
    As[(akoff + 2) * AS + arow] = av.z;
    As[(akoff + 3) * AS + arow] = av.w;
#pragma unroll
    for (int i = 0; i < BLD; i++) Bs[i * 256 + tid] = bv[i];
    __syncthreads();
#pragma unroll
    for (int kk = 0; kk < KT; kk++) {
      float4 a = *(const float4*)&As[kk * AS + tr * 4];
      float ar[4] = {a.x, a.y, a.z, a.w};
      float b[MC];
#pragma unroll
      for (int c = 0; c < MC; c++) b[c] = Bs[kk * M + tc * MC + c];
#pragma unroll
      for (int r = 0; r < 4; r++)
#pragma unroll
        for (int c = 0; c < MC; c++) acc[r][c] += ar[r] * b[c];
    }
  }

#pragma unroll
  for (int r = 0; r < 4; r++) {
    int row = r0 + tr * 4 + r;
    if (row < N) {
      float dsc = (EPI == 1) ? dinv[row] : 1.f;
#pragma unroll
      for (int c = 0; c < MC; c++) {
        int col = tc * MC + c;
        float v = acc[r][c];
        if (EPI == 0) Yf[(long)row * M + col] = v;
        else          Yb[(long)row * M + col] = f2b(v * dsc);
      }
    }
  }
}

// ---- pull aggregation -----------------------------------------------------
template<int C>
__global__ __launch_bounds__(256) void gcn_pull(const ushort_t* __restrict__ htn,
                                                const int* __restrict__ rowptr,
                                                const int* __restrict__ csr,
                                                const float* __restrict__ dinv,
                                                float* __restrict__ OUT, int N) {
  constexpr int NPBk = 256 / C;
  const int node = blockIdx.x * NPBk + threadIdx.x / C;
  const int c = threadIdx.x % C;
  if (node >= N) return;
  const int st = rowptr[node], en = rowptr[node + 1];
  float acc = b2f(htn[(long)node * C + c]);
  int j = st;
  for (; j + 4 <= en; j += 4) {
    int s0 = csr[j], s1 = csr[j + 1], s2 = csr[j + 2], s3 = csr[j + 3];
    float v0 = b2f(htn[(long)s0 * C + c]);
    float v1 = b2f(htn[(long)s1 * C + c]);
    float v2 = b2f(htn[(long)s2 * C + c]);
    float v3 = b2f(htn[(long)s3 * C + c]);
    acc += v0 + v1 + v2 + v3;
  }
  for (; j < en; j++) acc += b2f(htn[(long)csr[j] * C + c]);
  OUT[(long)node * C + c] = acc * dinv[node];
}

// ---- BN column stats ------------------------------------------------------
template<int C>
__global__ __launch_bounds__(256) void colstats(const float* __restrict__ H, int N,
                                                float* gsum, float* gsq) {
  constexpr int G = 256 / C;
  const int col = threadIdx.x % C, g = threadIdx.x / C;
  float s = 0.f, q = 0.f;
  for (long r = (long)blockIdx.x * G + g; r < N; r += (long)gridDim.x * G) {
    float v = H[r * C + col];
    s += v; q += v * v;
  }
  __shared__ float ls[256], lq[256];
  ls[threadIdx.x] = s; lq[threadIdx.x] = q;
  __syncthreads();
  if (threadIdx.x < C) {
#pragma unroll
    for (int i = 1; i < G; i++) { s += ls[col + i * C]; q += lq[col + i * C]; }
    atomAddF(&gsum[col], s);
    atomAddF(&gsq[col], q);
  }
}

__global__ void bn_finalize(const float* __restrict__ gsum, const float* __restrict__ gsq,
                            const float* __restrict__ gamma, const float* __restrict__ beta,
                            float* scale, float* shift, int C, float invN, float eps) {
  int c = threadIdx.x;
  if (c >= C) return;
  float mean = gsum[c] * invN;
  float var = fmaxf(gsq[c] * invN - mean * mean, 0.f);
  float sc = gamma[c] * rsqrtf(var + eps);
  scale[c] = sc;
  shift[c] = beta[c] - mean * sc;
}

// ---- BN apply (final layer only) ------------------------------------------
template<int C, int ACT>
__global__ __launch_bounds__(256) void bn_apply(const float* __restrict__ X, float* __restrict__ Y,
                                                const float* __restrict__ scale,
                                                const float* __restrict__ shift, long total) {
  long stride = (long)gridDim.x * 256;
  for (long i = (long)blockIdx.x * 256 + threadIdx.x; i < total; i += stride) {
    int c = (int)(i & (C - 1));
    float v = X[i] * scale[c] + shift[c];
    if (ACT == 1) v = fmaxf(v, 0.f);
    if (ACT == 2) v = v > 0.f ? v : (expf(v) - 1.f);
    Y[i] = v;
  }
}

// ---------------------------------------------------------------------------
extern "C" void kernel_launch(void* const* d_in, const int* in_sizes, int n_in,
                              void* d_out, int out_size, void* d_ws, size_t ws_size,
                              hipStream_t stream) {
  const float* x   = (const float*)d_in[0];
  const int* eidx  = (const int*)d_in[1];
  const float* W1  = (const float*)d_in[2];
  const float* g1  = (const float*)d_in[4];
  const float* be1 = (const float*)d_in[5];
  const float* W2  = (const float*)d_in[6];
  const float* g2  = (const float*)d_in[8];
  const float* be2 = (const float*)d_in[9];
  const float* Wg1 = (const float*)d_in[10];
  const float* g3  = (const float*)d_in[12];
  const float* be3 = (const float*)d_in[13];
  const float* Wg2 = (const float*)d_in[14];
  const float* g4  = (const float*)d_in[16];
  const float* be4 = (const float*)d_in[17];
  float* out = (float*)d_out;

  const int N = in_sizes[0] / 512;
  const int E = in_sizes[1] / 2;
  const int* src  = eidx;
  const int* dstp = eidx + E;
  const long Nl = N;
  const int NB = (N + NPB - 1) / NPB;

  float* ws = (float*)d_ws;
  float* h1 = ws;                        // N*128 f32 (pre-GEMM1: pair buffer)
  float* h2 = ws + Nl * 128;             // N*64 f32
  int* csr    = (int*)(ws + Nl * 192);   // E
  int* rowptr = csr + E;                 // N+1
  int* gcur   = rowptr + N + 1;          // 640
  int* bbase  = gcur + 640;              // 644
  float* dinv = (float*)(bbase + 644);   // N
  float* S    = dinv + N;
  float* sums = S;                       // 512
  float* sqs  = S + 512;                 // 512
  int* bcnt   = (int*)(S + 1024);        // 640
  float* scale = S + 1664;               // 512
  float* shift = S + 2176;               // 512
  ushort_t* Wt = (ushort_t*)(S + 2688);  // 128*512 bf16 (128 KB)

  int2* pair = (int2*)h1;                // E pairs (25.6MB)

  float* out1    = h1;                          // N*64 f32
  ushort_t* htn  = (ushort_t*)(h1 + Nl * 64);   // N*64 bf16
  ushort_t* htn2 = (ushort_t*)h2;               // N*32 bf16
  float* out2    = h2 + Nl * 32;                // N*32 f32

  // zero sums, sqs, bcnt in one shot
  hipMemsetAsync(S, 0, 1664 * sizeof(float), stream);

  const float invN = 1.0f / (float)N;
  const int gb  = (N + 63) / 64;
  const int chunk = (E + 255) / 256;

  // W1 -> bf16 transposed
  w1_prep<<<256, 256, 0, stream>>>(W1, Wt);

  // CSR + degree pipeline (zero E-scale global atomics)
  bucket_count<<<256, 256, 0, stream>>>(dstp, bcnt, E, NB, chunk);
  bucket_scan<<<1, 1024, 0, stream>>>(bcnt, bbase, gcur, NB, E);
  csr_bucket<<<256, 256, 0, stream>>>(src, dstp, gcur, pair, E, NB, chunk);
  bucket_node<<<NB, 256, 0, stream>>>(pair, bbase, rowptr, csr, dinv, N);

  // encoder L1: Linear(512,128) via bf16 MFMA; BN stats only
  mfma_gemm1<<<(N + 127) / 128, 256, 0, stream>>>(x, Wt, h1, N);
  colstats<128><<<1024, 256, 0, stream>>>(h1, N, sums + 0, sqs + 0);
  bn_finalize<<<1, 128, 0, stream>>>(sums + 0, sqs + 0, g1, be1, scale + 0, shift + 0, 128, invN, 1e-3f);

  // encoder L2: A = ELU(BN(h1)) fused
  gemm_tiled<128, 64, 0, 1><<<gb, 256, 0, stream>>>(h1, W2, h2, nullptr, nullptr, scale + 0, shift + 0, N);
  colstats<64><<<1024, 256, 0, stream>>>(h2, N, sums + 128, sqs + 128);
  bn_finalize<<<1, 128, 0, stream>>>(sums + 128, sqs + 128, g2, be2, scale + 128, shift + 128, 64, invN, 1e-3f);

  // gc1: A = ELU(BN(h2)) fused; epilogue htn = bf16(h@Wg1 * dinv)
  gemm_tiled<64, 64, 1, 1><<<gb, 256, 0, stream>>>(h2, Wg1, nullptr, htn, dinv, scale + 128, shift + 128, N);
  gcn_pull<64><<<(N + 3) / 4, 256, 0, stream>>>(htn, rowptr, csr, dinv, out1, N);
  colstats<64><<<1024, 256, 0, stream>>>(out1, N, sums + 256, sqs + 256);
  bn_finalize<<<1, 128, 0, stream>>>(sums + 256, sqs + 256, g3, be3, scale + 256, shift + 256, 64, invN, 1e-5f);

  // gc2: A = ReLU(BN(out1)) fused; epilogue htn2 = bf16(h@Wg2 * dinv)
  gemm_tiled<64, 32, 1, 2><<<gb, 256, 0, stream>>>(out1, Wg2, nullptr, htn2, dinv, scale + 256, shift + 256, N);
  gcn_pull<32><<<(N + 7) / 8, 256, 0, stream>>>(htn2, rowptr, csr, dinv, out2, N);
  colstats<32><<<1024, 256, 0, stream>>>(out2, N, sums + 384, sqs + 384);
  bn_finalize<<<1, 128, 0, stream>>>(sums + 384, sqs + 384, g4, be4, scale + 384, shift + 384, 32, invN, 1e-5f);
  bn_apply<32, 0><<<2048, 256, 0, stream>>>(out2, out, scale + 384, shift + 384, Nl * 32);
}